// Round 2
// baseline (182.572 us; speedup 1.0000x reference)
//
#include <hip/hip_runtime.h>
#include <stdint.h>

// Problem constants
//  B = 32768 samples, T_X = 4, K = 128, 64 groups x 512, out = (64,128,1,1024) fp32
typedef __attribute__((ext_vector_type(8))) short bf16x8;  // 8 bf16 in 4 VGPRs
typedef __attribute__((ext_vector_type(4))) float f32x4;

__device__ __forceinline__ unsigned short f2bf(float x) {
    union { float f; uint32_t u; } v; v.f = x;
    uint32_t r = v.u + 0x7FFFu + ((v.u >> 16) & 1u);   // RNE
    return (unsigned short)(r >> 16);
}
__device__ __forceinline__ uint32_t pack2bf(float a, float b) {
    return (uint32_t)f2bf(a) | ((uint32_t)f2bf(b) << 16);
}
__device__ __forceinline__ float bf2f(uint32_t lo) {
    union { uint32_t u; float f; } v; v.u = lo << 16; return v.f;
}
__device__ __forceinline__ float lrelu(float v) { return v > 0.f ? v : 0.01f * v; }

// ---------------------------------------------------------------------------
// K0: precompute (split-precision bf16 hi/lo pairs)
//   G[i][j]  = (1/sqrt(128)) * sum_o Wk[o,i]*Wq[o,j]            (128x128)
//   M[o][c]  = inv_sqrt2 * sum_k conv_w[o, base+k] * Wv[k, c&127] (128x256)
//   scale2[o] = gamma*rsqrt(var+eps);  bias2[o] = (conv_b-mean)*scale2 + beta
// ---------------------------------------------------------------------------
__global__ __launch_bounds__(256) void precompute_kernel(
    const float* __restrict__ Wq, const float* __restrict__ Wk,
    const float* __restrict__ Wv, const float* __restrict__ conv_w,
    const float* __restrict__ conv_b, const float* __restrict__ bn_gamma,
    const float* __restrict__ bn_beta, const float* __restrict__ bn_mean,
    const float* __restrict__ bn_var,
    unsigned short* __restrict__ Gh, unsigned short* __restrict__ Gl,
    unsigned short* __restrict__ Mh, unsigned short* __restrict__ Ml,
    float* __restrict__ scale2, float* __restrict__ bias2)
{
    if (blockIdx.x == 384) {                       // constants block
        int o = threadIdx.x;
        if (o < 128) {
            float sc = bn_gamma[o] * rsqrtf(bn_var[o] + 1e-5f);
            scale2[o] = sc;
            bias2[o]  = (conv_b[o] - bn_mean[o]) * sc + bn_beta[o];
        }
        return;
    }
    int gid  = blockIdx.x * 256 + threadIdx.x;
    int oi   = gid >> 1;
    int half = gid & 1;
    float sum = 0.f;
    if (oi < 16384) {                              // G element (i,j)
        int i = oi >> 7, j = oi & 127;
        const float* wk = Wk + half * 64 * 128 + i;
        const float* wq = Wq + half * 64 * 128 + j;
        #pragma unroll 8
        for (int o = 0; o < 64; ++o) sum += wk[o * 128] * wq[o * 128];
        sum += __shfl_xor(sum, 1);
        if (!half) {
            float val = sum * 0.08838834764831845f;        // 1/sqrt(128)
            unsigned short h = f2bf(val);
            Gh[i * 128 + j] = h;
            Gl[i * 128 + j] = f2bf(val - bf2f(h));
        }
    } else {                                       // M element (o,c)
        int rel = oi - 16384;
        int o = rel >> 8, c = rel & 255;
        const float* cw = conv_w + o * 256 + ((c >> 7) << 7) + half * 64;
        const float* wv = Wv + half * 64 * 128 + (c & 127);
        #pragma unroll 8
        for (int t = 0; t < 64; ++t) sum += cw[t] * wv[t * 128];
        sum += __shfl_xor(sum, 1);
        if (!half) {
            float val = sum * 0.7071067811865476f;         // inv_sqrt2
            unsigned short h = f2bf(val);
            Mh[o * 256 + c] = h;
            Ml[o * 256 + c] = f2bf(val - bf2f(h));
        }
    }
}

// ---------------------------------------------------------------------------
// K1: fully fused attention + IDWT + conv + BN + LeakyReLU
// One block = 64 consecutive samples = 128 consecutive output columns j.
//   bid: samples b in [64*bid, +64), out group g = bid>>3, j0 = (bid&7)*128.
//   (output row r = 2*b_loc + parity == j - j0)
// LDS (64 KB), all wave-private after the single barrier:
//   [0,32K):  phase 0 = y fp32 staging (64 x 512B, XOR-swizzled 16B granules)
//             phase 1+ = U-low bf16 tile (128 rows x 128 c, UADDR swizzle)
//   [32K,64K): phase 0b out = gbuf fp32 (64 x 128, row stride 512B)
//             phase 1+ = U-high bf16 tile (same UADDR swizzle)
// ---------------------------------------------------------------------------
#define UADDR(row, lane) (((row) << 8) + (((((lane) >> 2) ^ ((row) & 7))) << 4) + ((((lane) << 2)) & 15))
#define AADDR(row, gi)   (((row) << 8) + ((((gi) ^ ((row) & 7))) << 4))

__global__ __launch_bounds__(256) void fused_kernel(
    const float* __restrict__ x, const float* __restrict__ y,
    const unsigned short* __restrict__ Gh, const unsigned short* __restrict__ Gl,
    const unsigned short* __restrict__ Mh, const unsigned short* __restrict__ Ml,
    const float* __restrict__ scale2, const float* __restrict__ bias2,
    float* __restrict__ out)
{
    __shared__ __align__(16) unsigned char smem[65536];
    float* gbufF = (float*)(smem + 32768);

    const int tid = threadIdx.x;
    const int w = tid >> 6;          // wave 0..3
    const int l = tid & 63;          // lane
    const int quad = l >> 4;
    const int bid = blockIdx.x;
    const int b0 = bid * 64;

    // ---- Phase 0a: stage y rows [b0,b0+64) as fp32, 16B-granule XOR swizzle
    {
        const float* yb = y + (size_t)b0 * 128;
        #pragma unroll
        for (int it = 0; it < 8; ++it) {
            int idx = tid + it * 256;          // 2048 = 64 rows * 32 granules
            int row = idx >> 5, q = idx & 31;
            float4 v = *(const float4*)(yb + row * 128 + q * 4);
            *(float4*)(smem + row * 512 + ((q ^ (row & 7)) << 4)) = v;
        }
    }
    __syncthreads();    // the only block-wide barrier

    // ---- Phase 0b: g = Y @ G^T (split precision). Wave w owns samples [16w,16w+16)
    {
        f32x4 accg[8];
        #pragma unroll
        for (int nt = 0; nt < 8; ++nt) accg[nt] = (f32x4){0.f, 0.f, 0.f, 0.f};
        const int yrow = 16 * w + (l & 15);
        #pragma unroll
        for (int ks = 0; ks < 4; ++ks) {
            int g0 = ks * 8 + quad * 2;
            float4 v0 = *(const float4*)(smem + yrow * 512 + (((g0 + 0) ^ (yrow & 7)) << 4));
            float4 v1 = *(const float4*)(smem + yrow * 512 + (((g0 + 1) ^ (yrow & 7)) << 4));
            float f[8] = {v0.x, v0.y, v0.z, v0.w, v1.x, v1.y, v1.z, v1.w};
            union { bf16x8 v; unsigned short u[8]; } Ah, Al;
            #pragma unroll
            for (int j = 0; j < 8; ++j) {
                unsigned short h = f2bf(f[j]);
                Ah.u[j] = h;
                Al.u[j] = f2bf(f[j] - bf2f(h));
            }
            #pragma unroll
            for (int nt = 0; nt < 8; ++nt) {
                int off = (nt * 16 + (l & 15)) * 128 + ks * 32 + quad * 8;
                bf16x8 bh = *(const bf16x8*)(Gh + off);
                bf16x8 bl = *(const bf16x8*)(Gl + off);
                accg[nt] = __builtin_amdgcn_mfma_f32_16x16x32_bf16(Ah.v, bh, accg[nt], 0, 0, 0);
                accg[nt] = __builtin_amdgcn_mfma_f32_16x16x32_bf16(Al.v, bh, accg[nt], 0, 0, 0);
                accg[nt] = __builtin_amdgcn_mfma_f32_16x16x32_bf16(Ah.v, bl, accg[nt], 0, 0, 0);
            }
        }
        // C-frag: col = l&15 (=i), row = quad*4 + r (=sample) -> gbuf fp32
        #pragma unroll
        for (int nt = 0; nt < 8; ++nt) {
            int i = nt * 16 + (l & 15);
            #pragma unroll
            for (int r = 0; r < 4; ++r) {
                int srow = 16 * w + quad * 4 + r;
                gbufF[srow * 128 + i] = accg[nt][r];
            }
        }
    }
    // no barrier: everything below is wave-private (wave w touches only its
    // own Y rows [16w,16w+16) region, gbuf rows [16w,16w+16), U rows [32w,32w+32))

    // ---- Phase 1: dots (fp32) + softmax + build U (both halves to LDS)
    #pragma unroll 4
    for (int s = 0; s < 16; ++s) {
        int b_loc = w * 16 + s;
        const float2* xb = (const float2*)(x + (size_t)(b0 + b_loc) * 512);
        float2 x0 = xb[l], x1 = xb[64 + l], x2 = xb[128 + l], x3 = xb[192 + l];
        float2 g2 = *(const float2*)(gbufF + b_loc * 128 + 2 * l);
        float p0 = x0.x * g2.x + x0.y * g2.y;
        float p1 = x1.x * g2.x + x1.y * g2.y;
        float p2 = x2.x * g2.x + x2.y * g2.y;
        float p3 = x3.x * g2.x + x3.y * g2.y;
        #pragma unroll
        for (int off = 32; off >= 1; off >>= 1) {
            p0 += __shfl_xor(p0, off);
            p1 += __shfl_xor(p1, off);
            p2 += __shfl_xor(p2, off);
            p3 += __shfl_xor(p3, off);
        }
        float mx = fmaxf(fmaxf(p0, p1), fmaxf(p2, p3));
        float e0 = __expf(p0 - mx), e1 = __expf(p1 - mx);
        float e2 = __expf(p2 - mx), e3 = __expf(p3 - mx);
        float inv = 1.f / (e0 + e1 + e2 + e3);
        float w0 = e0 * inv, w1 = e1 * inv, w2 = e2 * inv, w3 = e3 * inv;
        int r0 = 2 * b_loc, r1 = r0 + 1;
        // U-low (c = 2l,2l+1): Haar even = +, odd = -
        *(uint32_t*)(smem + UADDR(r0, l)) = pack2bf(w0 * x0.x + w1 * x1.x, w0 * x0.y + w1 * x1.y);
        *(uint32_t*)(smem + UADDR(r1, l)) = pack2bf(w0 * x0.x - w1 * x1.x, w0 * x0.y - w1 * x1.y);
        // U-high overwrites gbuf rows just consumed (write depends on g2 -> ordered)
        *(uint32_t*)(smem + 32768 + UADDR(r0, l)) = pack2bf(w2 * x2.x + w3 * x3.x, w2 * x2.y + w3 * x3.y);
        *(uint32_t*)(smem + 32768 + UADDR(r1, l)) = pack2bf(w2 * x2.x - w3 * x3.x, w2 * x2.y - w3 * x3.y);
    }

    // ---- Phase 2: Z = U @ M^T, K=256 (low half region A, high half region B),
    //      M split hi/lo. Wave w owns U rows [32w,32w+32).
    f32x4 acc[2][8];
    #pragma unroll
    for (int m = 0; m < 2; ++m)
        #pragma unroll
        for (int nt = 0; nt < 8; ++nt) acc[m][nt] = (f32x4){0.f, 0.f, 0.f, 0.f};

    #pragma unroll
    for (int ks = 0; ks < 8; ++ks) {
        int half = ks >> 2, kk = ks & 3;
        int base = half << 15;                     // 0 or 32768
        int row0 = 32 * w + (l & 15);
        int row1 = row0 + 16;
        int gi = kk * 4 + quad;
        bf16x8 a0 = *(const bf16x8*)(smem + base + AADDR(row0, gi));
        bf16x8 a1 = *(const bf16x8*)(smem + base + AADDR(row1, gi));
        #pragma unroll
        for (int nt = 0; nt < 8; ++nt) {
            int off = (nt * 16 + (l & 15)) * 256 + half * 128 + kk * 32 + quad * 8;
            bf16x8 bh = *(const bf16x8*)(Mh + off);
            bf16x8 bl = *(const bf16x8*)(Ml + off);
            acc[0][nt] = __builtin_amdgcn_mfma_f32_16x16x32_bf16(a0, bh, acc[0][nt], 0, 0, 0);
            acc[0][nt] = __builtin_amdgcn_mfma_f32_16x16x32_bf16(a0, bl, acc[0][nt], 0, 0, 0);
            acc[1][nt] = __builtin_amdgcn_mfma_f32_16x16x32_bf16(a1, bh, acc[1][nt], 0, 0, 0);
            acc[1][nt] = __builtin_amdgcn_mfma_f32_16x16x32_bf16(a1, bl, acc[1][nt], 0, 0, 0);
        }
    }

    // ---- Epilogue: scale/bias/LeakyReLU, j-contiguous float4 stores
    {
        int out_g = bid >> 3;
        int j0 = (bid & 7) * 128;
        float* outp = out + (size_t)out_g * 131072 + j0;
        #pragma unroll
        for (int nt = 0; nt < 8; ++nt) {
            int o = nt * 16 + (l & 15);
            float sc = scale2[o], bi = bias2[o];
            #pragma unroll
            for (int m = 0; m < 2; ++m) {
                int jb = (2 * w + m) * 16 + quad * 4;
                f32x4 a = acc[m][nt];
                float4 r;
                r.x = lrelu(a[0] * sc + bi);
                r.y = lrelu(a[1] * sc + bi);
                r.z = lrelu(a[2] * sc + bi);
                r.w = lrelu(a[3] * sc + bi);
                *(float4*)(outp + (size_t)o * 1024 + jb) = r;
            }
        }
    }
}

extern "C" void kernel_launch(void* const* d_in, const int* in_sizes, int n_in,
                              void* d_out, int out_size, void* d_ws, size_t ws_size,
                              hipStream_t stream)
{
    (void)in_sizes; (void)n_in; (void)out_size; (void)ws_size;
    const float* x        = (const float*)d_in[0];
    const float* y        = (const float*)d_in[1];
    const float* Wq       = (const float*)d_in[2];
    const float* Wk       = (const float*)d_in[3];
    const float* Wv       = (const float*)d_in[4];
    const float* conv_w   = (const float*)d_in[5];
    const float* conv_b   = (const float*)d_in[6];
    const float* bn_gamma = (const float*)d_in[7];
    const float* bn_beta  = (const float*)d_in[8];
    const float* bn_mean  = (const float*)d_in[9];
    const float* bn_var   = (const float*)d_in[10];

    unsigned char* ws = (unsigned char*)d_ws;
    unsigned short* Gh = (unsigned short*)(ws);                // 32 KB
    unsigned short* Gl = (unsigned short*)(ws + 32768);        // 32 KB
    unsigned short* Mh = (unsigned short*)(ws + 65536);        // 64 KB
    unsigned short* Ml = (unsigned short*)(ws + 131072);       // 64 KB
    float* scale2      = (float*)(ws + 196608);                // 512 B
    float* bias2       = (float*)(ws + 197120);                // 512 B

    hipLaunchKernelGGL(precompute_kernel, dim3(385), dim3(256), 0, stream,
                       Wq, Wk, Wv, conv_w, conv_b, bn_gamma, bn_beta, bn_mean,
                       bn_var, Gh, Gl, Mh, Ml, scale2, bias2);
    hipLaunchKernelGGL(fused_kernel, dim3(512), dim3(256), 0, stream,
                       x, y, Gh, Gl, Mh, Ml, scale2, bias2, (float*)d_out);
}